// Round 1
// baseline (170.066 us; speedup 1.0000x reference)
//
#include <hip/hip_runtime.h>
#include <math.h>

#define N_NODES 50000
#define N_EDGES 800000
#define D_IN    64
#define H_HID   16
#define C_OUT   40

// ---------------- degree ----------------
__global__ void deg_kernel(const int* __restrict__ src, int* __restrict__ deg) {
    int e = blockIdx.x * blockDim.x + threadIdx.x;
    if (e < N_EDGES) atomicAdd(&deg[src[e]], 1);
}

__global__ void dinv_kernel(const int* __restrict__ deg, float* __restrict__ dinv) {
    int i = blockIdx.x * blockDim.x + threadIdx.x;
    if (i < N_NODES) {
        int d = deg[i];
        dinv[i] = (d > 0) ? rsqrtf((float)d) : 0.0f;
    }
}

// ---------------- xw0 = x@W1[0], xw1 = x@W1[1]  (N x 16 each) ----------------
__global__ void xw_kernel(const float* __restrict__ x, const float* __restrict__ W1,
                          float* __restrict__ xw0, float* __restrict__ xw1) {
    __shared__ float sW[2 * D_IN * H_HID];   // 8 KB
    for (int i = threadIdx.x; i < 2 * D_IN * H_HID; i += blockDim.x)
        sW[i] = W1[i];
    __syncthreads();

    int t = blockIdx.x * blockDim.x + threadIdx.x;
    if (t >= N_NODES * H_HID) return;
    int node = t / H_HID;
    int f    = t % H_HID;
    const float* xr = x + node * D_IN;
    float a0 = 0.f, a1 = 0.f;
    #pragma unroll
    for (int d = 0; d < D_IN; ++d) {
        float xv = xr[d];
        a0 += xv * sW[d * H_HID + f];
        a1 += xv * sW[D_IN * H_HID + d * H_HID + f];
    }
    xw0[t] = a0;
    xw1[t] = a1;
}

// ---------------- edge aggregation: agg[dst] += -dinv[s]*dinv[d] * feat[src] ----------------
__global__ void agg_kernel(const int* __restrict__ src, const int* __restrict__ dst,
                           const float* __restrict__ dinv,
                           const float* __restrict__ feat, float* __restrict__ agg) {
    long long t = (long long)blockIdx.x * blockDim.x + threadIdx.x;
    if (t >= (long long)N_EDGES * H_HID) return;
    int e = (int)(t / H_HID);
    int f = (int)(t % H_HID);
    int s = src[e];
    int d = dst[e];
    float w = -dinv[s] * dinv[d];
    atomicAdd(&agg[d * H_HID + f], w * feat[s * H_HID + f]);
}

// ---------------- layer1 epilogue: h = relu(xw0+agg1+b1); hw0 = h@W2[0] ----------------
__global__ void layer1_kernel(const float* __restrict__ xw0, const float* __restrict__ agg1,
                              const float* __restrict__ b1, const float* __restrict__ W2,
                              float* __restrict__ h, float* __restrict__ hw0) {
    __shared__ float sW[H_HID * C_OUT];   // W2[0], 2.5 KB
    __shared__ float sb[H_HID];
    for (int i = threadIdx.x; i < H_HID * C_OUT; i += blockDim.x) sW[i] = W2[i];
    if (threadIdx.x < H_HID) sb[threadIdx.x] = b1[threadIdx.x];
    __syncthreads();

    int node = blockIdx.x * blockDim.x + threadIdx.x;
    if (node >= N_NODES) return;
    float hv[H_HID];
    #pragma unroll
    for (int f = 0; f < H_HID; ++f) {
        float v = xw0[node * H_HID + f] + agg1[node * H_HID + f] + sb[f];
        v = (v > 0.f) ? v : 0.f;
        hv[f] = v;
        h[node * H_HID + f] = v;
    }
    #pragma unroll
    for (int c = 0; c < C_OUT; ++c) {
        float acc = 0.f;
        #pragma unroll
        for (int f = 0; f < H_HID; ++f) acc += hv[f] * sW[f * C_OUT + c];
        hw0[node * C_OUT + c] = acc;
    }
}

// ---------------- layer2 epilogue + log_softmax ----------------
__global__ void layer2_kernel(const float* __restrict__ hw0, const float* __restrict__ agg2,
                              const float* __restrict__ W2, const float* __restrict__ b2,
                              float* __restrict__ out) {
    __shared__ float sW[H_HID * C_OUT];   // W2[1]
    __shared__ float sb[C_OUT];
    for (int i = threadIdx.x; i < H_HID * C_OUT; i += blockDim.x)
        sW[i] = W2[H_HID * C_OUT + i];
    if (threadIdx.x < C_OUT) sb[threadIdx.x] = b2[threadIdx.x];
    __syncthreads();

    int node = blockIdx.x * blockDim.x + threadIdx.x;
    if (node >= N_NODES) return;
    float t1[H_HID];
    #pragma unroll
    for (int f = 0; f < H_HID; ++f) t1[f] = agg2[node * H_HID + f];

    float o[C_OUT];
    float mx = -1e30f;
    #pragma unroll
    for (int c = 0; c < C_OUT; ++c) {
        float acc = hw0[node * C_OUT + c] + sb[c];
        #pragma unroll
        for (int f = 0; f < H_HID; ++f) acc += t1[f] * sW[f * C_OUT + c];
        o[c] = acc;
        mx = fmaxf(mx, acc);
    }
    float sum = 0.f;
    #pragma unroll
    for (int c = 0; c < C_OUT; ++c) sum += expf(o[c] - mx);
    float lse = mx + logf(sum);
    #pragma unroll
    for (int c = 0; c < C_OUT; ++c) out[node * C_OUT + c] = o[c] - lse;
}

extern "C" void kernel_launch(void* const* d_in, const int* in_sizes, int n_in,
                              void* d_out, int out_size, void* d_ws, size_t ws_size,
                              hipStream_t stream) {
    const float* x   = (const float*)d_in[0];
    const int*   ei  = (const int*)d_in[1];
    const float* W1  = (const float*)d_in[2];
    const float* b1  = (const float*)d_in[3];
    const float* W2  = (const float*)d_in[4];
    const float* b2  = (const float*)d_in[5];
    float* out = (float*)d_out;

    const int* src = ei;            // edge_index[0]
    const int* dst = ei + N_EDGES;  // edge_index[1]

    // workspace layout (4-byte elements)
    float* ws   = (float*)d_ws;
    int*   deg  = (int*)ws;                         // N
    float* dinv = ws + (size_t)N_NODES;             // N
    float* xw0  = ws + (size_t)2  * N_NODES;        // N*16
    float* xw1  = ws + (size_t)18 * N_NODES;        // N*16
    float* agg1 = ws + (size_t)34 * N_NODES;        // N*16
    float* h    = ws + (size_t)50 * N_NODES;        // N*16
    float* hw0  = ws + (size_t)66 * N_NODES;        // N*40
    float* agg2 = ws + (size_t)106 * N_NODES;       // N*16

    hipMemsetAsync(deg,  0, (size_t)N_NODES * sizeof(int), stream);
    hipMemsetAsync(agg1, 0, (size_t)N_NODES * H_HID * sizeof(float), stream);
    hipMemsetAsync(agg2, 0, (size_t)N_NODES * H_HID * sizeof(float), stream);

    const int B = 256;
    deg_kernel<<<(N_EDGES + B - 1) / B, B, 0, stream>>>(src, deg);
    dinv_kernel<<<(N_NODES + B - 1) / B, B, 0, stream>>>(deg, dinv);
    xw_kernel<<<(N_NODES * H_HID + B - 1) / B, B, 0, stream>>>(x, W1, xw0, xw1);

    long long agg_threads = (long long)N_EDGES * H_HID;
    int agg_blocks = (int)((agg_threads + B - 1) / B);
    agg_kernel<<<agg_blocks, B, 0, stream>>>(src, dst, dinv, xw1, agg1);

    layer1_kernel<<<(N_NODES + B - 1) / B, B, 0, stream>>>(xw0, agg1, b1, W2, h, hw0);

    agg_kernel<<<agg_blocks, B, 0, stream>>>(src, dst, dinv, h, agg2);

    layer2_kernel<<<(N_NODES + B - 1) / B, B, 0, stream>>>(hw0, agg2, W2, b2, out);
}